// Round 1
// 128.107 us; speedup vs baseline: 1.0118x; 1.0118x over previous
//
#include <hip/hip_runtime.h>
#include <math.h>

#define ALPHA   0.5f
#define BATA    0.01f
#define LAMDA   0.01f
#define GAMA    0.01f
#define BB      4096
#define N_NEG   50
#define TOTAL_H 204800
#define DIM     64

// ---------------- phase 0: segment offsets
// offs[b] = first index i with hist_segids[i] >= b ; offs[BB] = TOTAL_H.
__global__ __launch_bounds__(256) void offs_kernel(
    const int* __restrict__ segids, int* __restrict__ offs)
{
    int i = blockIdx.x * 256 + threadIdx.x;
    if (i >= TOTAL_H) return;
    int s = segids[i];
    if (i == 0) {
        for (int b = 0; b <= s; ++b) offs[b] = 0;
    } else {
        int p = segids[i - 1];
        for (int b = p + 1; b <= s; ++b) offs[b] = i;
    }
    if (i == TOTAL_H - 1) {
        for (int b = s + 1; b <= BB; ++b) offs[b] = TOTAL_H;
    }
}

// ---------------- main: one 256-thread block (4 waves) per user.
// 16-lane groups (g = tid/16, sub = tid%16); lane sub owns dims [4*sub,4*sub+4).
// v2: neg qi rows / bi values are loaded AFTER the barrier (only their 4 int
// indices are carried across), so no gathered float4 data is live across
// __syncthreads(). Peak ~50 VGPR; __launch_bounds__(256,8) pins 8 waves/SIMD
// (32 waves/CU) for full latency hiding on the random row gathers.
__global__ __launch_bounds__(256, 8) void fism_kernel(
    const float* __restrict__ bu, const float* __restrict__ bi,
    const float* __restrict__ qi, const float* __restrict__ pu,
    const float* __restrict__ user_item_num,
    const int*  __restrict__ users, const int* __restrict__ pos_items,
    const int*  __restrict__ neg_items, const int* __restrict__ hist_items,
    const int*  __restrict__ offs,
    float* __restrict__ part)
{
    const int b    = blockIdx.x;
    const int tid  = threadIdx.x;
    const int lane = tid & 63;
    const int w    = tid >> 6;
    const int g    = tid >> 4;
    const int sub  = tid & 15;

    __shared__ float4 s_part[64];
    __shared__ float  s_loss[4];

    const float4* pu4 = (const float4*)pu;
    const float4* qi4 = (const float4*)qi;

    const int start = offs[b];
    const int end   = offs[b + 1];

    // ---- tier 1: all index / scalar loads (independent, issued up front)
    const int* nrow = neg_items + (size_t)b * N_NEG;
    int nidx[4];
    #pragma unroll
    for (int k = 0; k < 3; ++k) nidx[k] = nrow[g + 16 * k];
    // slot k=3 (j = 48+g) is only valid for g<2; alias invalid groups to their
    // own k=0 row: the duplicate gather is an L1 hit, loss term masked at end.
    const bool has4 = (g < 2);
    nidx[3] = nrow[has4 ? (48 + g) : g];

    const int   pit = pos_items[b];
    const float t   = rsqrtf(user_item_num[b]);
    const float b_u = bu[users[b]];
    const float bip = bi[pit];

    // 4 masked hist indices per group (covers count <= 64)
    int   hidx[4];
    float hm[4];
    #pragma unroll
    for (int k = 0; k < 4; ++k) {
        int ip  = start + g + 16 * k;
        bool v  = (ip < end);
        hm[k]   = v ? 1.f : 0.f;
        hidx[k] = hist_items[v ? ip : (TOTAL_H - 1)];
    }

    // pos row prefetch (needed right after the barrier; only 4 VGPR)
    const float4 qp = qi4[(size_t)pit * 16 + sub];

    // ---- hist row gathers -> per-group partial embed
    float4 acc = make_float4(0.f, 0.f, 0.f, 0.f);
    #pragma unroll
    for (int k = 0; k < 4; ++k) {
        float4 r = pu4[(size_t)hidx[k] * 16 + sub];
        acc.x += hm[k] * r.x; acc.y += hm[k] * r.y;
        acc.z += hm[k] * r.z; acc.w += hm[k] * r.w;
    }
    // block-uniform slow path: histories > 64 (~2% of blocks)
    if (end - start > 64) {
        for (int i = start + g + 64; i < end; i += 16) {
            float4 r = pu4[(size_t)hist_items[i] * 16 + sub];
            acc.x += r.x; acc.y += r.y; acc.z += r.z; acc.w += r.w;
        }
    }

    // reduce the 4 groups within this wave (xor lane bits 4,5)
    #pragma unroll
    for (int off = 16; off < 64; off <<= 1) {
        acc.x += __shfl_xor(acc.x, off, 64);
        acc.y += __shfl_xor(acc.y, off, 64);
        acc.z += __shfl_xor(acc.z, off, 64);
        acc.w += __shfl_xor(acc.w, off, 64);
    }
    if (lane < 16) s_part[w * 16 + lane] = acc;
    __syncthreads();

    float4 full = s_part[sub];
    {
        float4 p1 = s_part[16 + sub], p2 = s_part[32 + sub], p3 = s_part[48 + sub];
        full.x += p1.x + p2.x + p3.x;
        full.y += p1.y + p2.y + p3.y;
        full.z += p1.z + p2.z + p3.z;
        full.w += p1.w + p2.w + p3.w;
    }

    float loss = 0.f;

    // ---- negatives: issue the 4 qi-row + 4 bi gathers NOW (post-barrier)
    float4 nq0 = qi4[(size_t)nidx[0] * 16 + sub];
    float4 nq1 = qi4[(size_t)nidx[1] * 16 + sub];
    float4 nq2 = qi4[(size_t)nidx[2] * 16 + sub];
    float4 nq3 = qi4[(size_t)nidx[3] * 16 + sub];
    float  nb0 = bi[nidx[0]];
    float  nb1 = bi[nidx[1]];
    float  nb2 = bi[nidx[2]];
    float  nb3 = bi[nidx[3]];

    // ---- positive + per-user regularization (overlaps neg-load latency)
    {
        float pdot = full.x * qp.x + full.y * qp.y + full.z * qp.z + full.w * qp.w;
        float psq  = qp.x * qp.x + qp.y * qp.y + qp.z * qp.z + qp.w * qp.w;
        float uesq = full.x * full.x + full.y * full.y + full.z * full.z + full.w * full.w;
        #pragma unroll
        for (int off = 1; off < 16; off <<= 1) {
            pdot += __shfl_xor(pdot, off, 64);
            psq  += __shfl_xor(psq,  off, 64);
            uesq += __shfl_xor(uesq, off, 64);
        }
        if (tid == 0) {
            float s = 1.f / (1.f + __expf(-(t * pdot + bip + b_u)));
            loss += (1.f - s) * (1.f - s);
            loss += BATA * uesq + BATA * psq;
            loss += LAMDA * (bip * bip + GAMA * b_u * b_u);
        }
    }

    // ---- neg dots: 4 interleaved reduce chains over the 16-lane group
    {
        float d0 = full.x * nq0.x + full.y * nq0.y + full.z * nq0.z + full.w * nq0.w;
        float d1 = full.x * nq1.x + full.y * nq1.y + full.z * nq1.z + full.w * nq1.w;
        float d2 = full.x * nq2.x + full.y * nq2.y + full.z * nq2.z + full.w * nq2.w;
        float d3 = full.x * nq3.x + full.y * nq3.y + full.z * nq3.z + full.w * nq3.w;
        #pragma unroll
        for (int off = 1; off < 16; off <<= 1) {
            d0 += __shfl_xor(d0, off, 64);
            d1 += __shfl_xor(d1, off, 64);
            d2 += __shfl_xor(d2, off, 64);
            d3 += __shfl_xor(d3, off, 64);
        }
        if (sub == 0) {
            float s0 = 1.f / (1.f + __expf(-(t * d0 + nb0 + b_u)));
            float s1 = 1.f / (1.f + __expf(-(t * d1 + nb1 + b_u)));
            float s2 = 1.f / (1.f + __expf(-(t * d2 + nb2 + b_u)));
            float s3 = 1.f / (1.f + __expf(-(t * d3 + nb3 + b_u)));
            loss += s0 * s0 + s1 * s1 + s2 * s2;
            if (has4) loss += s3 * s3;
        }
    }

    // ---- block loss reduction: only lanes 0/16/32/48 are nonzero -> 2 levels
    loss += __shfl_xor(loss, 16, 64);
    loss += __shfl_xor(loss, 32, 64);
    if (lane == 0) s_loss[w] = loss;
    __syncthreads();
    if (tid == 0) part[b] = s_loss[0] + s_loss[1] + s_loss[2] + s_loss[3];
}

// ---------------- final: sum 4096 partials -> out[0] (single block, no atomics)
__global__ __launch_bounds__(256) void reduce_kernel(
    const float* __restrict__ part, float* __restrict__ out)
{
    const int tid  = threadIdx.x;
    const int lane = tid & 63;
    const int w    = tid >> 6;
    float s = 0.f;
    #pragma unroll
    for (int i = 0; i < BB / 256; ++i) s += part[tid + i * 256];
    #pragma unroll
    for (int off = 32; off > 0; off >>= 1) s += __shfl_xor(s, off, 64);
    __shared__ float sl[4];
    if (lane == 0) sl[w] = s;
    __syncthreads();
    if (tid == 0) out[0] = sl[0] + sl[1] + sl[2] + sl[3];
}

extern "C" void kernel_launch(void* const* d_in, const int* in_sizes, int n_in,
                              void* d_out, int out_size, void* d_ws, size_t ws_size,
                              hipStream_t stream) {
    const float* bu            = (const float*)d_in[0];
    const float* bi            = (const float*)d_in[1];
    const float* qi            = (const float*)d_in[2];
    const float* pu            = (const float*)d_in[3];
    const float* user_item_num = (const float*)d_in[4];
    const int*   users         = (const int*)d_in[5];
    const int*   pos_items     = (const int*)d_in[6];
    const int*   neg_items     = (const int*)d_in[7];
    const int*   hist_items    = (const int*)d_in[8];
    const int*   hist_segids   = (const int*)d_in[9];
    float* out  = (float*)d_out;

    int*   offs = (int*)d_ws;                         // BB+1 ints
    float* part = (float*)((char*)d_ws + (((BB + 2) * sizeof(int) + 255) & ~255)); // BB floats

    offs_kernel<<<(TOTAL_H + 255) / 256, 256, 0, stream>>>(hist_segids, offs);
    fism_kernel<<<BB, 256, 0, stream>>>(bu, bi, qi, pu, user_item_num,
                                        users, pos_items, neg_items,
                                        hist_items, offs, part);
    reduce_kernel<<<1, 256, 0, stream>>>(part, out);
}